// Round 2
// baseline (2912.307 us; speedup 1.0000x reference)
//
#include <hip/hip_runtime.h>

typedef __bf16 bf16x8 __attribute__((ext_vector_type(8)));
typedef float f32x4 __attribute__((ext_vector_type(4)));
typedef unsigned short u16;
typedef unsigned int u32;

#define WIN_N 49
#define CDIM 384
#define NHEADS 12
#define HDIM 32
#define SCALE 0.17677669529663687f
#define WTOK (WIN_N * CDIM)  // 18816 elems per window

__device__ __forceinline__ u16 f2bf(float f) {
  u32 u = __float_as_uint(f);
  u32 r = (u + 0x7FFFu + ((u >> 16) & 1u)) >> 16;
  return (u16)r;
}

// MFMA fragment load from row-major bf16 (stride in u16 elems, stride % 8 == 0).
// Zero for rows >= nrows. Verified gfx950 mapping: elem j = M[row][k0+quad*8+j].
__device__ __forceinline__ bf16x8 ld_frag(const u16* base, int row, int nrows,
                                          int stride, int k0, int quad) {
  bf16x8 z = {};
  if (row < nrows)
    z = *(const bf16x8*)(base + row * stride + k0 + quad * 8);
  return z;
}

// ---------------- prep: weights -> bf16, bias table gather ----------------
__global__ void prep_kernel(const float* __restrict__ qkv_w,
                            const float* __restrict__ proj_w,
                            const float* __restrict__ bias_table,
                            const int* __restrict__ rel_index,
                            u16* __restrict__ qkvWb, u16* __restrict__ projWb,
                            float* __restrict__ biasF) {
  int i = blockIdx.x * blockDim.x + threadIdx.x;
  int stride = gridDim.x * blockDim.x;
  for (int t = i; t < 3 * CDIM * CDIM; t += stride) qkvWb[t] = f2bf(qkv_w[t]);
  for (int t = i; t < CDIM * CDIM; t += stride) projWb[t] = f2bf(proj_w[t]);
  for (int t = i; t < NHEADS * WIN_N * WIN_N; t += stride) {
    int h = t / (WIN_N * WIN_N);
    int r = t - h * (WIN_N * WIN_N);
    biasF[t] = bias_table[rel_index[r] * NHEADS + h];
  }
}

// ---------------- fused window attention, 8 waves / block ----------------
// 1 block = 1 window. 512 threads = 8 waves, 2 blocks/CU (LDS 68.8 KB) ->
// 16 waves/CU (~50% occ) vs round-0's 8. Per head-group (2 heads, 6 groups):
//   QKV: wave -> (mt = w>>1, n-half = w&1 covering 6 16-col units). 1 LDS
//        A-fragment + 6 global weight tiles per k (half the redundancy of r0).
//   attn: wave -> (head hh = w>>2, m-tile amt = w&3). Softmax rows, P rows,
//        PV output and Og rows are all wave-private -> barrier (d) removed.
// Barriers/group: (a) reuse guard, (b) QKV ready, (c) P aliases Q/K, (f) Og.
__global__ void __launch_bounds__(512, 4)
swin_fused(const float* __restrict__ x, const float* __restrict__ qkv_b,
           const float* __restrict__ proj_b, const u16* __restrict__ qkvWb,
           const u16* __restrict__ projWb, const float* __restrict__ biasF,
           float* __restrict__ out) {
  // LDS map (u16): Xb@0 49x392 | Qb@19208 49x72 | Kb@22736 49x72
  //                Pb@19208 2x(49x72) (aliases Qb+Kb after barrier (c))
  //                Vt@26264 64x72 | Og@30872 49x72   -> 68,800 B total
  __shared__ __align__(16) u16 sm[34400];
  u16* Xb = sm;
  u16* Qb = sm + 19208;
  u16* Kb = sm + 22736;
  u16* Pb = sm + 19208;
  u16* Vt = sm + 26264;
  u16* Og = sm + 30872;

  const int tid = threadIdx.x;
  const int w = tid >> 6, lane = tid & 63, quad = lane >> 4, l16 = lane & 15;
  const int b = blockIdx.x;
  const int mt = w >> 1, nh = w & 1;   // QKV phase mapping
  const int hh = w >> 2, amt = w & 3;  // attention phase mapping

  // ---- stage X -> LDS bf16 (fp32 in, padded stride 392 for bank spread) ----
  const float4* xs = (const float4*)(x + (size_t)b * WTOK);
  for (int i = tid; i < WIN_N * 96; i += 512) {
    int m = i / 96, c4 = (i - m * 96) * 4;
    float4 v = xs[i];
    u32* dst = (u32*)(Xb + m * 392 + c4);
    dst[0] = (u32)f2bf(v.x) | ((u32)f2bf(v.y) << 16);
    dst[1] = (u32)f2bf(v.z) | ((u32)f2bf(v.w) << 16);
  }
  // zero Vt once (token cols 49..71 must stay 0 across all groups)
  for (int i = tid; i < (64 * 72) / 2; i += 512) ((u32*)Vt)[i] = 0u;

  // per-wave QKV unit mapping: 6 units of 16 cols; t = nh*6 + j
  int matv[6], colv[6], rowb[6];
#pragma unroll
  for (int j = 0; j < 6; ++j) {
    int t = nh * 6 + j;
    int chunk = t >> 1, half = t & 1;  // chunk: 0=Qh0 1=Qh1 2=Kh0 3=Kh1 4=Vh0 5=Vh1
    matv[j] = chunk >> 1;
    int hhc = chunk & 1;
    colv[j] = hhc * HDIM + half * 16 + l16;
    rowb[j] = matv[j] * CDIM + hhc * HDIM + half * 16 + l16;  // + g*64 later
  }

  f32x4 pacc[3][4];  // proj accumulators: 3 n-tiles (wave's 48 cols) x 4 m-tiles
#pragma unroll
  for (int t3 = 0; t3 < 3; ++t3)
#pragma unroll
    for (int m4 = 0; m4 < 4; ++m4) pacc[t3][m4] = (f32x4){0.f, 0.f, 0.f, 0.f};

  for (int g = 0; g < 6; ++g) {
    __syncthreads();  // (a) prior group done reading Pb/Vt/Og; X staged (g=0)

    // ---- QKV: 12 k-steps, 1 A-frag + 6 weight tiles per wave ----
    f32x4 acc[6];
#pragma unroll
    for (int j = 0; j < 6; ++j) acc[j] = (f32x4){0.f, 0.f, 0.f, 0.f};

    for (int k = 0; k < 12; ++k) {
      bf16x8 a = ld_frag(Xb, mt * 16 + l16, WIN_N, 392, k * 32, quad);
#pragma unroll
      for (int j = 0; j < 6; ++j) {
        bf16x8 bw = *(const bf16x8*)(qkvWb + (size_t)(rowb[j] + g * 64) * CDIM + k * 32 + quad * 8);
        acc[j] = __builtin_amdgcn_mfma_f32_16x16x32_bf16(a, bw, acc[j], 0, 0, 0);
      }
    }
#pragma unroll
    for (int j = 0; j < 6; ++j) {
      float bias = qkv_b[rowb[j] + g * 64];
      int col = colv[j];
#pragma unroll
      for (int r = 0; r < 4; ++r) {
        int tok = mt * 16 + quad * 4 + r;  // C/D row = quad*4 + reg
        if (tok < WIN_N) {
          u16 hv = f2bf(acc[j][r] + bias);
          if (matv[j] == 0)      Qb[tok * 72 + col] = hv;
          else if (matv[j] == 1) Kb[tok * 72 + col] = hv;
          else                   Vt[col * 72 + tok] = hv;  // transposed
        }
      }
    }
    __syncthreads();  // (b) Q,K,V ready

    // ---- S = Q @ K^T (wave: head hh, m-tile amt) ----
    bf16x8 aq = ld_frag(Qb, amt * 16 + l16, WIN_N, 72, hh * HDIM, quad);
    bf16x8 bk[4];
#pragma unroll
    for (int nt = 0; nt < 4; ++nt)
      bk[nt] = ld_frag(Kb, nt * 16 + l16, WIN_N, 72, hh * HDIM, quad);

    // hoist bias loads (global) so latency hides under the MFMAs below;
    // fold pad sentinels: n>=49 -> -1e30 (S there is exactly 0), m>=49 -> 0
    const int hglob = g * 2 + hh;
    const float* bp = biasF + (size_t)hglob * WIN_N * WIN_N;
    float bl[4][4];
#pragma unroll
    for (int r = 0; r < 4; ++r) {
      int m = amt * 16 + quad * 4 + r;
#pragma unroll
      for (int nt = 0; nt < 4; ++nt) {
        int n = nt * 16 + l16;
        bl[r][nt] = (m < WIN_N && n < WIN_N) ? bp[m * WIN_N + n]
                                             : ((m >= WIN_N) ? 0.f : -1e30f);
      }
    }

    f32x4 S[4];
#pragma unroll
    for (int nt = 0; nt < 4; ++nt) {
      f32x4 z = (f32x4){0.f, 0.f, 0.f, 0.f};
      S[nt] = __builtin_amdgcn_mfma_f32_16x16x32_bf16(aq, bk[nt], z, 0, 0, 0);
    }

    // ---- softmax (row lives in one 16-lane quad group; registers only) ----
#pragma unroll
    for (int r = 0; r < 4; ++r) {
      float v[4];
#pragma unroll
      for (int nt = 0; nt < 4; ++nt) v[nt] = S[nt][r] * SCALE + bl[r][nt];
      float mx = fmaxf(fmaxf(v[0], v[1]), fmaxf(v[2], v[3]));
      mx = fmaxf(mx, __shfl_xor(mx, 1));
      mx = fmaxf(mx, __shfl_xor(mx, 2));
      mx = fmaxf(mx, __shfl_xor(mx, 4));
      mx = fmaxf(mx, __shfl_xor(mx, 8));
      float sum = 0.f;
#pragma unroll
      for (int nt = 0; nt < 4; ++nt) {
        v[nt] = __expf(v[nt] - mx);
        sum += v[nt];
      }
      sum += __shfl_xor(sum, 1);
      sum += __shfl_xor(sum, 2);
      sum += __shfl_xor(sum, 4);
      sum += __shfl_xor(sum, 8);
      float inv = 1.f / sum;
#pragma unroll
      for (int nt = 0; nt < 4; ++nt) S[nt][r] = v[nt] * inv;
    }
    __syncthreads();  // (c) all waves done reading Qb/Kb -> safe to alias P

    // ---- write P (wave-private rows: own m-tile, own head) ----
    u16* Ph = Pb + hh * 3528;
#pragma unroll
    for (int nt = 0; nt < 4; ++nt)
#pragma unroll
      for (int r = 0; r < 4; ++r) {
        int m = amt * 16 + quad * 4 + r;
        if (m < WIN_N) Ph[m * 72 + nt * 16 + l16] = f2bf(S[nt][r]);
      }

    // ---- O = P @ V (reads own P rows: same-wave LDS RAW, no barrier) ----
    f32x4 o2[2];
    o2[0] = (f32x4){0.f, 0.f, 0.f, 0.f};
    o2[1] = (f32x4){0.f, 0.f, 0.f, 0.f};
    bf16x8 ap[2];
#pragma unroll
    for (int kk = 0; kk < 2; ++kk)
      ap[kk] = ld_frag(Ph, amt * 16 + l16, WIN_N, 72, kk * 32, quad);
#pragma unroll
    for (int kk = 0; kk < 2; ++kk)
#pragma unroll
      for (int nt2 = 0; nt2 < 2; ++nt2) {
        bf16x8 bv = ld_frag(Vt, hh * HDIM + nt2 * 16 + l16, 64, 72, kk * 32, quad);
        o2[nt2] = __builtin_amdgcn_mfma_f32_16x16x32_bf16(ap[kk], bv, o2[nt2], 0, 0, 0);
      }
    // ---- write Og (wave-private rows) ----
#pragma unroll
    for (int nt2 = 0; nt2 < 2; ++nt2)
#pragma unroll
      for (int r = 0; r < 4; ++r) {
        int tok = amt * 16 + quad * 4 + r;
        if (tok < WIN_N)
          Og[tok * 72 + hh * HDIM + nt2 * 16 + l16] = f2bf(o2[nt2][r]);
      }
    __syncthreads();  // (f) Og ready

    // ---- proj accumulate: pacc += Og @ projW[:, g*64 : g*64+64]^T ----
#pragma unroll
    for (int kk = 0; kk < 2; ++kk) {
      bf16x8 ao[4];
#pragma unroll
      for (int m4 = 0; m4 < 4; ++m4)
        ao[m4] = ld_frag(Og, m4 * 16 + l16, WIN_N, 72, kk * 32, quad);
#pragma unroll
      for (int t3 = 0; t3 < 3; ++t3) {
        int nrow = w * 48 + t3 * 16 + l16;
        bf16x8 bw = *(const bf16x8*)(projWb + (size_t)nrow * CDIM + g * 64 + kk * 32 + quad * 8);
#pragma unroll
        for (int m4 = 0; m4 < 4; ++m4)
          pacc[t3][m4] = __builtin_amdgcn_mfma_f32_16x16x32_bf16(ao[m4], bw, pacc[t3][m4], 0, 0, 0);
      }
    }
  }

  // ---- epilogue ----
  float* outp = out + (size_t)b * WTOK;
#pragma unroll
  for (int t3 = 0; t3 < 3; ++t3) {
    int n = w * 48 + t3 * 16 + l16;
    float pb = proj_b[n];
#pragma unroll
    for (int m4 = 0; m4 < 4; ++m4)
#pragma unroll
      for (int r = 0; r < 4; ++r) {
        int m = m4 * 16 + quad * 4 + r;
        if (m < WIN_N) outp[m * CDIM + n] = pacc[t3][m4][r] + pb;
      }
  }
}

extern "C" void kernel_launch(void* const* d_in, const int* in_sizes, int n_in,
                              void* d_out, int out_size, void* d_ws, size_t ws_size,
                              hipStream_t stream) {
  const float* x          = (const float*)d_in[0];
  const float* qkv_w      = (const float*)d_in[1];
  const float* qkv_b      = (const float*)d_in[2];
  const float* proj_w     = (const float*)d_in[3];
  const float* proj_b     = (const float*)d_in[4];
  const float* bias_table = (const float*)d_in[5];
  const int*   rel_index  = (const int*)d_in[6];

  // ws layout: qkv_w bf16 (884,736 B) | proj_w bf16 (294,912 B) | biasF fp32 (115,248 B)
  u16* qkvWb = (u16*)d_ws;
  u16* projWb = qkvWb + 3 * CDIM * CDIM;
  float* biasF = (float*)(projWb + CDIM * CDIM);

  hipLaunchKernelGGL(prep_kernel, dim3(512), dim3(256), 0, stream,
                     qkv_w, proj_w, bias_table, rel_index, qkvWb, projWb, biasF);
  hipLaunchKernelGGL(swin_fused, dim3(4096), dim3(512), 0, stream,
                     x, qkv_b, proj_b, qkvWb, projWb, biasF, (float*)d_out);
}

// Round 3
// 2089.242 us; speedup vs baseline: 1.3940x; 1.3940x over previous
//
#include <hip/hip_runtime.h>

typedef __bf16 bf16x8 __attribute__((ext_vector_type(8)));
typedef float f32x4 __attribute__((ext_vector_type(4)));
typedef unsigned short u16;
typedef unsigned int u32;

#define WIN_N 49
#define CDIM 384
#define NHEADS 12
#define HDIM 32
#define SCALE 0.17677669529663687f

__device__ __forceinline__ u16 f2bf(float f) {
  u32 u = __float_as_uint(f);
  u32 r = (u + 0x7FFFu + ((u >> 16) & 1u)) >> 16;
  return (u16)r;
}

// MFMA fragment load from row-major bf16 (stride in u16 elems, stride % 8 == 0
// so each 16B read is aligned). Zero for rows >= nrows.
// Verified gfx950 mapping: elem j of lane = M[row][k0 + quad*8 + j].
__device__ __forceinline__ bf16x8 ld_frag(const u16* base, int row, int nrows,
                                          int stride, int k0, int quad) {
  bf16x8 z = {};
  if (row < nrows)
    z = *(const bf16x8*)(base + row * stride + k0 + quad * 8);
  return z;
}

// ---------------- prep: weights -> bf16, bias table gather ----------------
__global__ void prep_kernel(const float* __restrict__ qkv_w,
                            const float* __restrict__ proj_w,
                            const float* __restrict__ bias_table,
                            const int* __restrict__ rel_index,
                            u16* __restrict__ qkvWb, u16* __restrict__ projWb,
                            float* __restrict__ biasF) {
  int i = blockIdx.x * blockDim.x + threadIdx.x;
  int stride = gridDim.x * blockDim.x;
  for (int t = i; t < 3 * CDIM * CDIM; t += stride) qkvWb[t] = f2bf(qkv_w[t]);
  for (int t = i; t < CDIM * CDIM; t += stride) projWb[t] = f2bf(proj_w[t]);
  for (int t = i; t < NHEADS * WIN_N * WIN_N; t += stride) {
    int h = t / (WIN_N * WIN_N);
    int r = t - h * (WIN_N * WIN_N);
    biasF[t] = bias_table[rel_index[r] * NHEADS + h];
  }
}

// ---------------- fused window attention (round-0 dataflow + pipelining) ----
// 1 block = 1 window. 256 threads = 4 waves, 2 blocks/CU (LDS 68.8 KB).
// vs round-0: barrier (d) removed (P rows wave-private, same-wave RAW);
// QKV weight loads 2-stage software-pipelined; proj weights prefetched across
// barrier (f); bias loads hoisted to group top (complete under QKV compute).
__global__ void __launch_bounds__(256, 2)
swin_fused(const float* __restrict__ x, const float* __restrict__ qkv_b,
           const float* __restrict__ proj_b, const u16* __restrict__ qkvWb,
           const u16* __restrict__ projWb, const float* __restrict__ biasF,
           float* __restrict__ out) {
  // LDS map (u16 elems):
  //  Xb  @ 0      : 49 x 392  = 19208   (stride 392: 784B rows -> 4-dword bank stagger)
  //  Qb  @ 19208  : 49 x 72   = 3528    (cols: head0 d0..31 | head1 d0..31)
  //  Kb  @ 22736  : 49 x 72   = 3528
  //  Pb  @ 19208  : 2 x 49x72           (aliases Qb+Kb after barrier (c))
  //  Vt  @ 26264  : 64 x 72   = 4608    (row = group-local feature, col = token)
  //  Og  @ 30872  : 49 x 72   = 3528
  __shared__ __align__(16) u16 sm[34400];  // 68,800 B -> 2 blocks/CU
  u16* Xb = sm;
  u16* Qb = sm + 19208;
  u16* Kb = sm + 22736;
  u16* Pb = sm + 19208;
  u16* Vt = sm + 26264;
  u16* Og = sm + 30872;

  const int tid = threadIdx.x;
  const int w = tid >> 6, lane = tid & 63, quad = lane >> 4, l16 = lane & 15;
  const int b = blockIdx.x;
  const int mhalf = w & 1, hh = w >> 1;  // attention: wave -> (head hh, M-half)

  // ---- stage X -> LDS bf16 ----
  const float4* xs = (const float4*)(x + (size_t)b * (WIN_N * CDIM));
  for (int i = tid; i < WIN_N * (CDIM / 4); i += 256) {
    int m = i / 96, c4 = (i - m * 96) * 4;
    float4 v = xs[i];
    u32* dst = (u32*)(Xb + m * 392 + c4);
    dst[0] = (u32)f2bf(v.x) | ((u32)f2bf(v.y) << 16);
    dst[1] = (u32)f2bf(v.z) | ((u32)f2bf(v.w) << 16);
  }
  // zero Vt once (token cols 49..71 must stay 0 across all groups)
  for (int i = tid; i < (64 * 72) / 2; i += 256) ((u32*)Vt)[i] = 0u;

  // per-wave QKV col-tile mapping (12 units of 16 cols, 3/wave -> each weight
  // tile loaded exactly ONCE per block: best MFMA:load ratio, best L2 reuse)
  int mat[3], hhc[3], half[3], rowb[3];
#pragma unroll
  for (int tl = 0; tl < 3; ++tl) {
    int t = w * 3 + tl;
    int chunk = t >> 1;       // 0..5
    half[tl] = t & 1;         // which 16-col half of the 32
    mat[tl] = chunk >> 1;     // 0=Q 1=K 2=V
    hhc[tl] = chunk & 1;      // head within group
    rowb[tl] = mat[tl] * CDIM + hhc[tl] * HDIM + half[tl] * 16 + l16;  // + g*64
  }

  f32x4 pacc[6][4];  // proj accumulators: 6 N-tiles (wave's 96 cols) x 4 M-tiles
#pragma unroll
  for (int t6 = 0; t6 < 6; ++t6)
#pragma unroll
    for (int mt = 0; mt < 4; ++mt) pacc[t6][mt] = (f32x4){0.f, 0.f, 0.f, 0.f};

#define LOADW(dst, kk)                                                        \
  _Pragma("unroll") for (int tl = 0; tl < 3; ++tl) dst[tl] =                  \
      *(const bf16x8*)(qkvWb + (size_t)(rowb[tl] + g * 64) * CDIM + (kk)*32 + \
                       quad * 8);

  for (int g = 0; g < 6; ++g) {
    // ---- hoisted loads: bias for this group's softmax + first weight stage.
    // Issued BEFORE barrier (a): the compiler's vmcnt drain at the barrier
    // means they complete during the barrier wait, costing nothing.
    const int hglob = g * 2 + hh;
    const float* bp = biasF + (size_t)hglob * WIN_N * WIN_N;
    float bl[2][4][4];
#pragma unroll
    for (int mt2 = 0; mt2 < 2; ++mt2)
#pragma unroll
      for (int r = 0; r < 4; ++r) {
        int m = (2 * mhalf + mt2) * 16 + quad * 4 + r;
#pragma unroll
        for (int nt = 0; nt < 4; ++nt) {
          int n = nt * 16 + l16;
          bl[mt2][r][nt] = (m < WIN_N && n < WIN_N)
                               ? bp[m * WIN_N + n]
                               : ((m >= WIN_N) ? 0.f : -1e30f);
        }
      }
    bf16x8 bwA[3], bwB[3];
    LOADW(bwA, 0);

    __syncthreads();  // (a) prior group done with Pb/Vt/Og; Xb staged (g=0)

    // ---- QKV: 12 k-steps, 2-stage weight pipeline, fully unrolled ----
    f32x4 acc[3][4];
#pragma unroll
    for (int tl = 0; tl < 3; ++tl)
#pragma unroll
      for (int mt = 0; mt < 4; ++mt) acc[tl][mt] = (f32x4){0.f, 0.f, 0.f, 0.f};

#pragma unroll
    for (int k2 = 0; k2 < 6; ++k2) {
      const int k0 = 2 * k2, k1 = 2 * k2 + 1;
      LOADW(bwB, k1);  // in flight while k0's MFMAs run
      {
        bf16x8 a[4];
#pragma unroll
        for (int mt = 0; mt < 4; ++mt)
          a[mt] = ld_frag(Xb, mt * 16 + l16, WIN_N, 392, k0 * 32, quad);
#pragma unroll
        for (int tl = 0; tl < 3; ++tl)
#pragma unroll
          for (int mt = 0; mt < 4; ++mt)
            acc[tl][mt] = __builtin_amdgcn_mfma_f32_16x16x32_bf16(a[mt], bwA[tl], acc[tl][mt], 0, 0, 0);
      }
      if (k2 < 5) LOADW(bwA, k0 + 2);  // in flight while k1's MFMAs run
      {
        bf16x8 a[4];
#pragma unroll
        for (int mt = 0; mt < 4; ++mt)
          a[mt] = ld_frag(Xb, mt * 16 + l16, WIN_N, 392, k1 * 32, quad);
#pragma unroll
        for (int tl = 0; tl < 3; ++tl)
#pragma unroll
          for (int mt = 0; mt < 4; ++mt)
            acc[tl][mt] = __builtin_amdgcn_mfma_f32_16x16x32_bf16(a[mt], bwB[tl], acc[tl][mt], 0, 0, 0);
      }
    }
#pragma unroll
    for (int tl = 0; tl < 3; ++tl) {
      float bias = qkv_b[rowb[tl] + g * 64];
      int col = hhc[tl] * HDIM + half[tl] * 16 + l16;
#pragma unroll
      for (int mt = 0; mt < 4; ++mt)
#pragma unroll
        for (int r = 0; r < 4; ++r) {
          int tok = mt * 16 + quad * 4 + r;  // C/D row = quad*4 + reg
          if (tok < WIN_N) {
            u16 hv = f2bf(acc[tl][mt][r] + bias);
            if (mat[tl] == 0)      Qb[tok * 72 + col] = hv;
            else if (mat[tl] == 1) Kb[tok * 72 + col] = hv;
            else                   Vt[col * 72 + tok] = hv;  // transposed
          }
        }
    }
    __syncthreads();  // (b) Q,K,V ready

    // ---- S = Q @ K^T (per wave: head hh, M-tiles {2*mhalf, 2*mhalf+1}) ----
    f32x4 S[2][4];
    bf16x8 aq[2];
#pragma unroll
    for (int mt2 = 0; mt2 < 2; ++mt2)
      aq[mt2] = ld_frag(Qb, (2 * mhalf + mt2) * 16 + l16, WIN_N, 72, hh * HDIM, quad);
#pragma unroll
    for (int nt = 0; nt < 4; ++nt) {
      bf16x8 bk = ld_frag(Kb, nt * 16 + l16, WIN_N, 72, hh * HDIM, quad);
#pragma unroll
      for (int mt2 = 0; mt2 < 2; ++mt2) {
        f32x4 z = (f32x4){0.f, 0.f, 0.f, 0.f};
        S[mt2][nt] = __builtin_amdgcn_mfma_f32_16x16x32_bf16(aq[mt2], bk, z, 0, 0, 0);
      }
    }
    // ---- softmax over rows (bias already in registers) ----
#pragma unroll
    for (int mt2 = 0; mt2 < 2; ++mt2)
#pragma unroll
      for (int r = 0; r < 4; ++r) {
        float v[4];
#pragma unroll
        for (int nt = 0; nt < 4; ++nt) v[nt] = S[mt2][nt][r] * SCALE + bl[mt2][r][nt];
        float mx = fmaxf(fmaxf(v[0], v[1]), fmaxf(v[2], v[3]));
        mx = fmaxf(mx, __shfl_xor(mx, 1));
        mx = fmaxf(mx, __shfl_xor(mx, 2));
        mx = fmaxf(mx, __shfl_xor(mx, 4));
        mx = fmaxf(mx, __shfl_xor(mx, 8));
        float sum = 0.f;
#pragma unroll
        for (int nt = 0; nt < 4; ++nt) {
          v[nt] = __expf(v[nt] - mx);
          sum += v[nt];
        }
        sum += __shfl_xor(sum, 1);
        sum += __shfl_xor(sum, 2);
        sum += __shfl_xor(sum, 4);
        sum += __shfl_xor(sum, 8);
        float inv = 1.f / sum;
#pragma unroll
        for (int nt = 0; nt < 4; ++nt) S[mt2][nt][r] = v[nt] * inv;
      }
    __syncthreads();  // (c) all waves done reading Qb/Kb -> safe to alias P

    // ---- write P (bf16) into Qb/Kb region; cols 49..63 are exact zeros.
    // Rows are wave-private (own m-half) and re-read by the SAME wave below:
    // same-wave LDS RAW needs no barrier (old barrier (d) removed). ----
    u16* Ph = Pb + hh * 3528;
#pragma unroll
    for (int mt2 = 0; mt2 < 2; ++mt2)
#pragma unroll
      for (int nt = 0; nt < 4; ++nt)
#pragma unroll
        for (int r = 0; r < 4; ++r) {
          int m = (2 * mhalf + mt2) * 16 + quad * 4 + r;
          if (m < WIN_N) Ph[m * 72 + nt * 16 + l16] = f2bf(S[mt2][nt][r]);
        }

    // ---- O = P @ V (Vt reads ordered by (b); P reads same-wave) ----
    f32x4 o2[2][2];
#pragma unroll
    for (int mt2 = 0; mt2 < 2; ++mt2)
#pragma unroll
      for (int nt2 = 0; nt2 < 2; ++nt2) o2[mt2][nt2] = (f32x4){0.f, 0.f, 0.f, 0.f};
    bf16x8 bv[2][2];
#pragma unroll
    for (int nt2 = 0; nt2 < 2; ++nt2)
#pragma unroll
      for (int kk = 0; kk < 2; ++kk)
        bv[nt2][kk] = ld_frag(Vt, hh * HDIM + nt2 * 16 + l16, 64, 72, kk * 32, quad);
#pragma unroll
    for (int mt2 = 0; mt2 < 2; ++mt2)
#pragma unroll
      for (int kk = 0; kk < 2; ++kk) {
        bf16x8 ap = ld_frag(Ph, (2 * mhalf + mt2) * 16 + l16, WIN_N, 72, kk * 32, quad);
#pragma unroll
        for (int nt2 = 0; nt2 < 2; ++nt2)
          o2[mt2][nt2] = __builtin_amdgcn_mfma_f32_16x16x32_bf16(ap, bv[nt2][kk], o2[mt2][nt2], 0, 0, 0);
      }
    // ---- write Og (bf16, cols = group-local feature) ----
#pragma unroll
    for (int mt2 = 0; mt2 < 2; ++mt2)
#pragma unroll
      for (int nt2 = 0; nt2 < 2; ++nt2)
#pragma unroll
        for (int r = 0; r < 4; ++r) {
          int tok = (2 * mhalf + mt2) * 16 + quad * 4 + r;
          if (tok < WIN_N)
            Og[tok * 72 + hh * HDIM + nt2 * 16 + l16] = f2bf(o2[mt2][nt2][r]);
        }

    // ---- prefetch proj weights kk=0 BEFORE barrier (f): they complete
    // during the barrier's vmcnt drain ----
    bf16x8 pb0[6];
#pragma unroll
    for (int t6 = 0; t6 < 6; ++t6)
      pb0[t6] = *(const bf16x8*)(projWb + (size_t)(w * 96 + t6 * 16 + l16) * CDIM + g * 64 + quad * 8);

    __syncthreads();  // (f) Og ready

    // ---- proj accumulate: pacc += Og @ projW[:, g*64 : g*64+64]^T ----
    bf16x8 pb1[6];
#pragma unroll
    for (int t6 = 0; t6 < 6; ++t6)
      pb1[t6] = *(const bf16x8*)(projWb + (size_t)(w * 96 + t6 * 16 + l16) * CDIM + g * 64 + 32 + quad * 8);
    {
      bf16x8 ao[4];
#pragma unroll
      for (int mt = 0; mt < 4; ++mt)
        ao[mt] = ld_frag(Og, mt * 16 + l16, WIN_N, 72, 0, quad);
#pragma unroll
      for (int t6 = 0; t6 < 6; ++t6)
#pragma unroll
        for (int mt = 0; mt < 4; ++mt)
          pacc[t6][mt] = __builtin_amdgcn_mfma_f32_16x16x32_bf16(ao[mt], pb0[t6], pacc[t6][mt], 0, 0, 0);
    }
    {
      bf16x8 ao[4];
#pragma unroll
      for (int mt = 0; mt < 4; ++mt)
        ao[mt] = ld_frag(Og, mt * 16 + l16, WIN_N, 72, 32, quad);
#pragma unroll
      for (int t6 = 0; t6 < 6; ++t6)
#pragma unroll
        for (int mt = 0; mt < 4; ++mt)
          pacc[t6][mt] = __builtin_amdgcn_mfma_f32_16x16x32_bf16(ao[mt], pb1[t6], pacc[t6][mt], 0, 0, 0);
    }
  }

  // ---- epilogue ----
  float* outp = out + (size_t)b * (WIN_N * CDIM);
#pragma unroll
  for (int t6 = 0; t6 < 6; ++t6) {
    int n = w * 96 + t6 * 16 + l16;
    float pb = proj_b[n];
#pragma unroll
    for (int mt = 0; mt < 4; ++mt)
#pragma unroll
      for (int r = 0; r < 4; ++r) {
        int m = mt * 16 + quad * 4 + r;
        if (m < WIN_N) outp[m * CDIM + n] = pacc[t6][mt][r] + pb;
      }
  }
}

extern "C" void kernel_launch(void* const* d_in, const int* in_sizes, int n_in,
                              void* d_out, int out_size, void* d_ws, size_t ws_size,
                              hipStream_t stream) {
  const float* x          = (const float*)d_in[0];
  const float* qkv_w      = (const float*)d_in[1];
  const float* qkv_b      = (const float*)d_in[2];
  const float* proj_w     = (const float*)d_in[3];
  const float* proj_b     = (const float*)d_in[4];
  const float* bias_table = (const float*)d_in[5];
  const int*   rel_index  = (const int*)d_in[6];

  // ws layout: qkv_w bf16 (884,736 B) | proj_w bf16 (294,912 B) | biasF fp32 (115,248 B)
  u16* qkvWb = (u16*)d_ws;
  u16* projWb = qkvWb + 3 * CDIM * CDIM;
  float* biasF = (float*)(projWb + CDIM * CDIM);

  hipLaunchKernelGGL(prep_kernel, dim3(512), dim3(256), 0, stream,
                     qkv_w, proj_w, bias_table, rel_index, qkvWb, projWb, biasF);
  hipLaunchKernelGGL(swin_fused, dim3(4096), dim3(256), 0, stream,
                     x, qkv_b, proj_b, qkvWb, projWb, biasF, (float*)d_out);
}